// Round 19
// baseline (68.082 us; speedup 1.0000x reference)
//
#include <hip/hip_runtime.h>

namespace {

constexpr int B = 4, S = 4096, H = 16, D = 32;
constexpr int L = 32;             // chunk length
constexpr int NC = S / L;         // 128 chunks per sequence
constexpr int NBH = B * H;        // 64
constexpr int RS = H * D;         // 512 floats between consecutive time steps
constexpr int NSEG = 32;          // segments per (b,h)
constexpr int SEGC = NC / NSEG;   // 4 chunks per segment (= 1 group)
constexpr float GEPS = 1.52587890625e-05f;  // 2^-16 per-step decay clamp

// Lore (rounds 6-18, measured):
//  - launch_bounds(256,w) caps VGPR ~256/w; cap < live set => GB-scale spill.
//  - Scalar j-loops over LDS tiles are LDS-instruction bound -> MFMA.
//  - COLD scalar column loads are latency death (r13); OK L3-warm (r12).
//  - KVc needs TOTAL-scaled W (x 2^{es4[3]-es4[sub]}), r16.
//  - r17/r18: neither 4 blocks/CU nor fewer barriers moved kB; kA (15KB LDS,
//    62% occ) hits 5.4TB/s with the same math -> kB was occupancy-starved
//    (40KB LDS + grid 4/CU). This round: LDS 23KB (W via shfl, kv bf16),
//    NSEG 32 -> grid 2048, single group (no state-update barriers).
//  - MFMA operand convention (HW-verified r12, absmax 0.5):
//    A-op: row = lane&31, k = 8*(lane>>5)+e (+16 for 2nd MFMA)
//    B-op: col = lane&31, same k
//    C/D : col = lane&31, row = (reg&3)+8*(reg>>2)+4*(lane>>5)

typedef __attribute__((ext_vector_type(8)))  short short8v;   // 8 bf16 = 4 VGPR
typedef __attribute__((ext_vector_type(16))) float f32x16;    // 16 f32 acc

__device__ __forceinline__ float flog2(float x) { return __builtin_amdgcn_logf(x); }
__device__ __forceinline__ float fexp2(float x) { return __builtin_amdgcn_exp2f(x); }
__device__ __forceinline__ unsigned f2bfu(float f) {          // fp32 -> bf16 (RNE)
    unsigned u = __float_as_uint(f);
    return (u + 0x7FFFu + ((u >> 16) & 1u)) >> 16;
}
__device__ __forceinline__ short f2bf(float f) { return (short)f2bfu(f); }
__device__ __forceinline__ float bf2f(short s) {              // bf16 -> fp32
    return __uint_as_float(((unsigned)(ushort)s) << 16);
}

// ---------------- Kernel A: segment summaries (structure verified r16-18) -----
__global__ __launch_bounds__(256)
void kA_segsum(const float* __restrict__ Kp, const float* __restrict__ Vp,
               const float* __restrict__ Gp, float* __restrict__ SegKV,
               float* __restrict__ SegLT)
{
    __shared__ __align__(16) float  k_s[L][36];
    __shared__ __align__(16) float  lg[L][36];
    __shared__ __align__(16) ushort w_s[L][40];
    __shared__ float sub[8][D];
    __shared__ float totr[D];
    __shared__ float S_lds[D][33];
    __shared__ float ltot[D];

    const int blk = blockIdx.x;              // bh*NSEG + seg
    const int bh = blk / NSEG, seg = blk % NSEG;
    const int b = bh >> 4, h = bh & (H - 1);

    const int tid = threadIdx.x;
    const int i = tid >> 3;
    const int u = (tid & 7) * 4;
    const int m = tid & 31, t = tid >> 5;
    const int r0 = t * 4;

    #pragma unroll
    for (int z = 0; z < 4; ++z) S_lds[i][u + z] = 0.f;
    if (tid < D) ltot[tid] = 0.f;

    for (int cc = 0; cc < SEGC; ++cc) {
        const int c = seg * SEGC + cc;
        const long base = ((long)b * S + (long)c * L) * RS + h * D;
        const long roff = base + (long)i * RS + u;
        float4 k4 = *(const float4*)(Kp + roff);
        float4 v4 = *(const float4*)(Vp + roff);
        float4 g4 = *(const float4*)(Gp + roff);
        __syncthreads();
        *(float4*)&k_s[i][u] = k4;
        float4 lv;
        lv.x = flog2(fmaxf(g4.x, GEPS));
        lv.y = flog2(fmaxf(g4.y, GEPS));
        lv.z = flog2(fmaxf(g4.z, GEPS));
        lv.w = flog2(fmaxf(g4.w, GEPS));
        *(float4*)&lg[i][u] = lv;
        __syncthreads();                     // b1

        float c0 = lg[r0 + 0][m];
        float c1 = c0 + lg[r0 + 1][m];
        float c2 = c1 + lg[r0 + 2][m];
        float c3 = c2 + lg[r0 + 3][m];
        sub[t][m] = c3;
        __syncthreads();                     // b2

        {
            float sb[8];
            float total = 0.f;
            #pragma unroll
            for (int tt = 0; tt < 8; ++tt) { sb[tt] = sub[tt][m]; total += sb[tt]; }
            float base_l = 0.f;
            #pragma unroll
            for (int tt = 0; tt < 8; ++tt) { if (tt < t) base_l += sb[tt]; }
            lg[r0 + 0][m] = base_l + c0;
            lg[r0 + 1][m] = base_l + c1;
            lg[r0 + 2][m] = base_l + c2;
            lg[r0 + 3][m] = base_l + c3;
            if (t == 0) { totr[m] = total; ltot[m] += total; }
        }
        __syncthreads();                     // b3

        {
            float4 l4 = *(float4*)&lg[i][u];
            float4 t4 = *(float4*)&totr[u];
            unsigned p0 = f2bfu(v4.x * fexp2(t4.x - l4.x))
                        | (f2bfu(v4.y * fexp2(t4.y - l4.y)) << 16);
            unsigned p1 = f2bfu(v4.z * fexp2(t4.z - l4.z))
                        | (f2bfu(v4.w * fexp2(t4.w - l4.w)) << 16);
            uint2 pp; pp.x = p0; pp.y = p1;
            *(uint2*)&w_s[i][u] = pp;
        }
        __syncthreads();                     // b4

        if (tid < 64) {
            const int half = tid >> 5;
            const int mm = tid & 31;
            short8v ka0, ka1, wf0, wf1;
            #pragma unroll
            for (int e = 0; e < 8; ++e) {
                ka0[e] = f2bf(k_s[8 * half + e][mm]);
                ka1[e] = f2bf(k_s[16 + 8 * half + e][mm]);
                wf0[e] = (short)w_s[8 * half + e][mm];
                wf1[e] = (short)w_s[16 + 8 * half + e][mm];
            }
            f32x16 acc;
            #pragma unroll
            for (int e = 0; e < 16; ++e) acc[e] = 0.f;
            acc = __builtin_amdgcn_mfma_f32_32x32x16_bf16(ka0, wf0, acc, 0, 0, 0);
            acc = __builtin_amdgcn_mfma_f32_32x32x16_bf16(ka1, wf1, acc, 0, 0, 0);
            const float gs = fexp2(totr[mm]);
            #pragma unroll
            for (int reg = 0; reg < 16; ++reg) {
                const int r = (reg & 3) + 8 * (reg >> 2) + 4 * half;
                S_lds[r][mm] = gs * S_lds[r][mm] + acc[reg];
            }
        }
    }
    __syncthreads();

    {
        float4 sv;
        sv.x = S_lds[i][u + 0]; sv.y = S_lds[i][u + 1];
        sv.z = S_lds[i][u + 2]; sv.w = S_lds[i][u + 3];
        *(float4*)(SegKV + (long)blk * (D * D) + i * D + u) = sv;
    }
    if (tid < D) SegLT[blk * D + tid] = ltot[tid];
}

// ---------------- Kernel B: compose + outputs (lean LDS, single group) -------
// One block per (bh, seg); wave wv handles chunk seg*4+wv.
// LDS ~23KB: a_s (union lt8) + kv_s bf16 + S_lds + totc. W via shfl exchange.
__global__ __launch_bounds__(256)
void kB_out(const float* __restrict__ Qp, const float* __restrict__ Kp,
            const float* __restrict__ Vp, const float* __restrict__ Gp,
            const float* __restrict__ SegKV, const float* __restrict__ SegLT,
            float* __restrict__ Op)
{
    __shared__ union AU {                            // lt8 dead before a_s live
        ushort a_s[4][L][40];                        // b128 row reads (80B rows)
        float  lt8[NSEG][D];                         // 4KB <= 10KB
    } au;
    __shared__ ushort kv_s[4][L][34];                // chunk KV bf16 (pad 34)
    __shared__ float S_lds[D][32];                   // segment-start state
    __shared__ float totc[4][D];                     // per-chunk gate totals

    const int blk = blockIdx.x;
    const int bh = blk / NSEG, seg = blk % NSEG;
    const int b = bh >> 4, h = bh & (H - 1);

    const int tid = threadIdx.x;
    const int wv = tid >> 6;
    const int lane = tid & 63;
    const int half = lane >> 5;
    const int m = lane & 31;

    // stage SegLT for this bh (NSEG*D = 1024 floats)
    for (int z = tid; z < NSEG * D; z += 256)
        au.lt8[z >> 5][z & 31] = SegLT[bh * NSEG * D + z];
    __syncthreads();

    // compose segment-start state from prior segment summaries (log space)
    {
        const int d = tid >> 3;
        const int u4 = (tid & 7) * 4;
        float4 Sv = {0, 0, 0, 0};
        float r0 = 0.f, r1 = 0.f, r2 = 0.f, r3 = 0.f;
        for (int sp = seg - 1; sp >= 0; --sp) {
            float4 kv = *(const float4*)(SegKV + (long)(bh * NSEG + sp) * (D * D)
                                         + d * D + u4);
            Sv.x += kv.x * fexp2(r0); Sv.y += kv.y * fexp2(r1);
            Sv.z += kv.z * fexp2(r2); Sv.w += kv.w * fexp2(r3);
            r0 += au.lt8[sp][u4 + 0]; r1 += au.lt8[sp][u4 + 1];
            r2 += au.lt8[sp][u4 + 2]; r3 += au.lt8[sp][u4 + 3];
        }
        S_lds[d][u4 + 0] = Sv.x; S_lds[d][u4 + 1] = Sv.y;
        S_lds[d][u4 + 2] = Sv.z; S_lds[d][u4 + 3] = Sv.w;
    }
    __syncthreads();    // lt8 dead; S_lds ready

    const int c = seg * SEGC + wv;
    const long base = ((long)b * S + (long)c * L) * RS + h * D;

    // ======== phase 1: no block barriers (same-wave LDS + shfl only) ========
    const float* qrow = Qp + base + (long)m * RS + 8 * half;
    const float* krow = Kp + base + (long)m * RS + 8 * half;
    float4 qv0 = *(const float4*)(qrow);
    float4 qv1 = *(const float4*)(qrow + 4);
    float4 qv2 = *(const float4*)(qrow + 16);
    float4 qv3 = *(const float4*)(qrow + 20);
    float4 kv0 = *(const float4*)(krow);
    float4 kv1 = *(const float4*)(krow + 4);
    float4 kv2 = *(const float4*)(krow + 16);
    float4 kv3 = *(const float4*)(krow + 20);
    short8v qa0, qa1, kb0, kb1;
    {
        float qf[16] = {qv0.x,qv0.y,qv0.z,qv0.w, qv1.x,qv1.y,qv1.z,qv1.w,
                        qv2.x,qv2.y,qv2.z,qv2.w, qv3.x,qv3.y,qv3.z,qv3.w};
        float kf[16] = {kv0.x,kv0.y,kv0.z,kv0.w, kv1.x,kv1.y,kv1.z,kv1.w,
                        kv2.x,kv2.y,kv2.z,kv2.w, kv3.x,kv3.y,kv3.z,kv3.w};
        #pragma unroll
        for (int e = 0; e < 8; ++e) {
            qa0[e] = f2bf(qf[e]);     qa1[e] = f2bf(qf[8 + e]);
            kb0[e] = f2bf(kf[e]);     kb1[e] = f2bf(kf[8 + e]);
        }
    }

    // per-lane register cumsum of own half-column; cross-half via shfl
    float cum[16];
    {
        const float* gcol = Gp + base + (long)(half * 16) * RS + m;
        float run = 0.f;
        #pragma unroll
        for (int t = 0; t < 16; ++t) {
            run += flog2(fmaxf(gcol[(long)t * RS], GEPS));
            cum[t] = run;
        }
    }
    {
        const float oth = __shfl_xor(cum[15], 32);
        if (half) {
            #pragma unroll
            for (int t = 0; t < 16; ++t) cum[t] += oth;
        }
    }
    const float c7 = cum[7], c15 = cum[15];
    const float o7 = __shfl_xor(c7, 32), o15 = __shfl_xor(c15, 32);
    float es4[4];
    es4[0] = half ? o7  : c7;
    es4[1] = half ? o15 : c15;
    es4[2] = half ? c7  : o7;
    es4[3] = half ? c15 : o15;
    if (half) totc[wv][m] = cum[15];     // chunk total per col

    // li at C-rows via 8 paired exchanges
    float li[16];
    #pragma unroll
    for (int j = 0; j < 8; ++j) {
        const int tl = (j & 3) + 8 * (j >> 2);     // 0..3, 8..11
        const float send = half ? cum[tl] : cum[tl + 4];
        const float recv = __shfl_xor(send, 32);
        li[j]     = half ? recv        : cum[tl];
        li[j + 8] = half ? cum[tl + 4] : recv;
    }

    // W rows [16*half .. 16*half+15] in registers (bf16 pairs), then build
    // B-fragments via one half-exchange (no LDS):
    //   lane(half=0) owns rows 0-15, needs wfk0=rows0-7(own), wfk1=rows16-23(other)
    //   lane(half=1) owns rows16-31, needs wfk0=rows8-15(other), wfk1=rows24-31(own)
    unsigned wpk[8];
    {
        const float* vcol = Vp + base + (long)(half * 16) * RS + m;
        #pragma unroll
        for (int j = 0; j < 8; ++j) {
            const int t0 = 2 * j, t1 = 2 * j + 1;
            const float e0 = (t0 < 8) ? c7 : c15;
            const float e1 = (t1 < 8) ? c7 : c15;
            const float w0 = vcol[(long)t0 * RS] * fexp2(e0 - cum[t0]);
            const float w1 = vcol[(long)t1 * RS] * fexp2(e1 - cum[t1]);
            wpk[j] = f2bfu(w0) | (f2bfu(w1) << 16);
        }
    }
    short8v wfk0, wfk1;
    {
        unsigned xf[4], rc[4];
        #pragma unroll
        for (int j = 0; j < 4; ++j) xf[j] = half ? wpk[j] : wpk[4 + j];
        #pragma unroll
        for (int j = 0; j < 4; ++j) rc[j] = (unsigned)__shfl_xor((int)xf[j], 32);
        uint4 w0u, w1u;
        w0u.x = half ? rc[0] : wpk[0];  w0u.y = half ? rc[1] : wpk[1];
        w0u.z = half ? rc[2] : wpk[2];  w0u.w = half ? rc[3] : wpk[3];
        w1u.x = half ? wpk[4] : rc[0];  w1u.y = half ? wpk[5] : rc[1];
        w1u.z = half ? wpk[6] : rc[2];  w1u.w = half ? wpk[7] : rc[3];
        wfk0 = *(short8v*)&w0u;
        wfk1 = *(short8v*)&w1u;
    }

    // Gram A = Q.K^T -> masked bf16 a_s (same-wave slot)
    {
        f32x16 acc;
        #pragma unroll
        for (int e = 0; e < 16; ++e) acc[e] = 0.f;
        acc = __builtin_amdgcn_mfma_f32_32x32x16_bf16(qa0, kb0, acc, 0, 0, 0);
        acc = __builtin_amdgcn_mfma_f32_32x32x16_bf16(qa1, kb1, acc, 0, 0, 0);
        #pragma unroll
        for (int reg = 0; reg < 16; ++reg) {
            const int irow = (reg & 3) + 8 * (reg >> 2) + 4 * half;
            const float av = (m <= irow) ? acc[reg] : 0.f;
            au.a_s[wv][irow][m] = (ushort)f2bf(av);
        }
    }

    // TOTAL-scaled W for KVc (r16 fix), then KVc = K^T . W_total -> kv_s bf16
    {
        const float fac0 = fexp2(es4[3] - es4[half]);
        const float fac1 = fexp2(es4[3] - es4[2 + half]);
        short8v wkv0, wkv1;
        #pragma unroll
        for (int e = 0; e < 8; ++e) {
            wkv0[e] = f2bf(bf2f(wfk0[e]) * fac0);
            wkv1[e] = f2bf(bf2f(wfk1[e]) * fac1);
        }
        f32x16 kvacc;
        #pragma unroll
        for (int e = 0; e < 16; ++e) kvacc[e] = 0.f;
        const float* kcol = Kp + base + m;
        short8v kta0, kta1;
        #pragma unroll
        for (int e = 0; e < 8; ++e) {
            kta0[e] = f2bf(kcol[(long)(8 * half + e) * RS]);
            kta1[e] = f2bf(kcol[(long)(16 + 8 * half + e) * RS]);
        }
        kvacc = __builtin_amdgcn_mfma_f32_32x32x16_bf16(kta0, wkv0, kvacc, 0, 0, 0);
        kvacc = __builtin_amdgcn_mfma_f32_32x32x16_bf16(kta1, wkv1, kvacc, 0, 0, 0);
        #pragma unroll
        for (int reg = 0; reg < 16; ++reg) {
            const int r = (reg & 3) + 8 * (reg >> 2) + 4 * half;
            kv_s[wv][r][m] = (ushort)f2bf(kvacc[reg]);
        }
    }

    __syncthreads();                       // B_a: kv_s, totc, a_s visible

    // ======== phase 2: parallel compose + outputs ========
    const float T0 = totc[0][m], T1 = totc[1][m],
                T2 = totc[2][m], T3 = totc[3][m];
    (void)T3;
    const float PS1 = T0, PS2 = T0 + T1, PS3 = T0 + T1 + T2;
    const float Pw = (wv == 0) ? 0.f : (wv == 1) ? PS1
                   : (wv == 2) ? PS2 : PS3;
    const float cpre = fexp2(Pw);

    float sfA[8], sfB[8];
    #pragma unroll
    for (int e = 0; e < 8; ++e) {
        sfA[e] = cpre * S_lds[8 * half + e][m];
        sfB[e] = cpre * S_lds[16 + 8 * half + e][m];
    }
    #pragma unroll
    for (int s = 0; s < 3; ++s) {
        if (s < wv) {                       // wave-uniform
            const float PSs = (s == 0) ? PS1 : (s == 1) ? PS2 : PS3;
            const float cs = fexp2(Pw - PSs);
            #pragma unroll
            for (int e = 0; e < 8; ++e) {
                sfA[e] += cs * bf2f((short)kv_s[s][8 * half + e][m]);
                sfB[e] += cs * bf2f((short)kv_s[s][16 + 8 * half + e][m]);
            }
        }
    }
    short8v sf0, sf1;
    #pragma unroll
    for (int e = 0; e < 8; ++e) {
        sf0[e] = f2bf(sfA[e]);
        sf1[e] = f2bf(sfB[e]);
    }

    // QS0 + epilogue
    f32x16 sacc;
    #pragma unroll
    for (int e = 0; e < 16; ++e) sacc[e] = 0.f;
    sacc = __builtin_amdgcn_mfma_f32_32x32x16_bf16(qa0, sf0, sacc, 0, 0, 0);
    sacc = __builtin_amdgcn_mfma_f32_32x32x16_bf16(qa1, sf1, sacc, 0, 0, 0);
    f32x16 out;
    #pragma unroll
    for (int reg = 0; reg < 16; ++reg) out[reg] = fexp2(li[reg]) * sacc[reg];

    #pragma unroll
    for (int ks = 0; ks < 2; ++ks) {
        const short8v af = *(const short8v*)&au.a_s[wv][m][16 * ks + 8 * half];
        const short8v wf = ks ? wfk1 : wfk0;
        #pragma unroll
        for (int par = 0; par < 2; ++par) {
            const int s = 2 * ks + par;
            short8v am;
            #pragma unroll
            for (int e = 0; e < 8; ++e) am[e] = (half == par) ? af[e] : (short)0;
            f32x16 p;
            #pragma unroll
            for (int e = 0; e < 16; ++e) p[e] = 0.f;
            p = __builtin_amdgcn_mfma_f32_32x32x16_bf16(am, wf, p, 0, 0, 0);
            #pragma unroll
            for (int reg = 0; reg < 16; ++reg)
                out[reg] += fexp2(fminf(li[reg] - es4[s], 120.f)) * p[reg];
        }
    }
    #pragma unroll
    for (int reg = 0; reg < 16; ++reg) {
        const int irow = (reg & 3) + 8 * (reg >> 2) + 4 * half;
        Op[base + (long)irow * RS + m] = out[reg];
    }
}

} // namespace

extern "C" void kernel_launch(void* const* d_in, const int* in_sizes, int n_in,
                              void* d_out, int out_size, void* d_ws, size_t ws_size,
                              hipStream_t stream)
{
    const float* q = (const float*)d_in[0];
    const float* k = (const float*)d_in[1];
    const float* v = (const float*)d_in[2];
    const float* g = (const float*)d_in[3];
    float* out = (float*)d_out;

    float* SegKV = (float*)d_ws;                        // [2048][32][32] f32 (8.4 MB)
    float* SegLT = SegKV + (long)NBH * NSEG * D * D;    // [2048][32]      (256 KB)

    dim3 blk(256);
    kA_segsum<<<dim3(NBH * NSEG), blk, 0, stream>>>(k, v, g, SegKV, SegLT);
    kB_out<<<dim3(NBH * NSEG), blk, 0, stream>>>(q, k, v, g, SegKV, SegLT, out);
}

// Round 20
// 62.048 us; speedup vs baseline: 1.0973x; 1.0973x over previous
//
#include <hip/hip_runtime.h>

namespace {

constexpr int B = 4, S = 4096, H = 16, D = 32;
constexpr int L = 32;             // chunk length
constexpr int NC = S / L;         // 128 chunks per sequence
constexpr int NBH = B * H;        // 64
constexpr int RS = H * D;         // 512 floats between consecutive time steps
constexpr float GEPS = 1.52587890625e-05f;  // 2^-16 per-step decay clamp

// Lore (rounds 6-19, measured):
//  - launch_bounds(256,w) caps VGPR ~256/w; cap < live set => GB-scale spill.
//  - Scalar j-loops over LDS tiles are LDS-instruction bound -> MFMA.
//  - COLD scalar column loads are latency death (r13); OK L3-warm (r12).
//  - KVc needs TOTAL-scaled W (r15 bug / r16 fix).
//  - r16-19: FOUR structural rewrites of a fused consumer (relay, barriers,
//    LDS, grid) all pinned at ~48us -> recomputing chunk-KV + state compose
//    in the consumer costs ~20us intrinsically. Keep consumer PURE (r12-k3)
//    and cut the scan round-trip by PRECISION: chunk-KV & S0 in bf16
//    (k3 casts S0 to bf16 for MFMA anyway; bf16 KV passed absmax 0.5 in r18).
//  - MFMA operand convention (HW-verified r12, absmax 0.5):
//    A-op: row = lane&31, k = 8*(lane>>5)+e (+16 for 2nd MFMA)
//    B-op: col = lane&31, same k
//    C/D : col = lane&31, row = (reg&3)+8*(reg>>2)+4*(lane>>5)

typedef __attribute__((ext_vector_type(8)))  short short8v;   // 8 bf16 = 4 VGPR
typedef __attribute__((ext_vector_type(16))) float f32x16;    // 16 f32 acc

__device__ __forceinline__ float flog2(float x) { return __builtin_amdgcn_logf(x); }
__device__ __forceinline__ float fexp2(float x) { return __builtin_amdgcn_exp2f(x); }
__device__ __forceinline__ unsigned f2bfu(float f) {          // fp32 -> bf16 (RNE)
    unsigned u = __float_as_uint(f);
    return (u + 0x7FFFu + ((u >> 16) & 1u)) >> 16;
}
__device__ __forceinline__ short f2bf(float f) { return (short)f2bfu(f); }
__device__ __forceinline__ float bf2f(short s) {              // bf16 -> fp32
    return __uint_as_float(((unsigned)(ushort)s) << 16);
}

// ---------------- Kernel 1: staged loads + column scan + MFMA tail ------------
// One block per chunk (8192). r14-verified body; output ChKV in bf16.
// W[i][m] = v[i][m]*2^{total[m]-l_i[m]};  ChKV[chunk][d][m] = sum_j K[j][d]W[j][m]
// ChG[chunk][m] = 2^{total[m]}
__global__ __launch_bounds__(256)
void k1_stage(const float* __restrict__ Kp, const float* __restrict__ Vp,
              const float* __restrict__ Gp, ushort* __restrict__ ChKV,
              float* __restrict__ ChG)
{
    __shared__ __align__(16) float  k_s[L][36];
    __shared__ __align__(16) float  lg[L][36];
    __shared__ __align__(16) ushort w_s[L][40];
    __shared__ float sub[8][D];
    __shared__ float totr[D];

    const int blk = blockIdx.x;                   // == chunk == bh*NC + c
    const int bh = blk >> 7;
    const int c = blk & (NC - 1);
    const int b = bh >> 4;
    const int h = bh & (H - 1);
    const long base = ((long)b * S + (long)c * L) * RS + h * D;

    const int tid = threadIdx.x;
    const int i = tid >> 3;          // row 0..31
    const int u = (tid & 7) * 4;     // col quad
    const long roff = base + (long)i * RS + u;

    float4 k4 = *(const float4*)(Kp + roff);
    float4 v4 = *(const float4*)(Vp + roff);
    float4 g4 = *(const float4*)(Gp + roff);
    *(float4*)&k_s[i][u] = k4;
    float4 lv;
    lv.x = flog2(fmaxf(g4.x, GEPS));
    lv.y = flog2(fmaxf(g4.y, GEPS));
    lv.z = flog2(fmaxf(g4.z, GEPS));
    lv.w = flog2(fmaxf(g4.w, GEPS));
    *(float4*)&lg[i][u] = lv;
    __syncthreads();                               // b1

    // column scan: thread -> (column m, 4-row group t)
    const int m = tid & 31, t = tid >> 5;
    const int r0 = t * 4;
    float c0 = lg[r0 + 0][m];
    float c1 = c0 + lg[r0 + 1][m];
    float c2 = c1 + lg[r0 + 2][m];
    float c3 = c2 + lg[r0 + 3][m];
    sub[t][m] = c3;
    __syncthreads();                               // b2

    {
        float sb[8];
        float total = 0.f;
        #pragma unroll
        for (int tt = 0; tt < 8; ++tt) { sb[tt] = sub[tt][m]; total += sb[tt]; }
        float base_l = 0.f;
        #pragma unroll
        for (int tt = 0; tt < 8; ++tt) { if (tt < t) base_l += sb[tt]; }
        lg[r0 + 0][m] = base_l + c0;
        lg[r0 + 1][m] = base_l + c1;
        lg[r0 + 2][m] = base_l + c2;
        lg[r0 + 3][m] = base_l + c3;
        if (t == 0) totr[m] = total;
        if (t == 1) ChG[(long)blk * D + m] = fexp2(total);
    }
    __syncthreads();                               // b3

    // W elementwise in row layout: v4 still in registers
    {
        float4 l4 = *(float4*)&lg[i][u];
        float4 t4 = *(float4*)&totr[u];            // broadcast across rows
        unsigned p0 = f2bfu(v4.x * fexp2(t4.x - l4.x))
                    | (f2bfu(v4.y * fexp2(t4.y - l4.y)) << 16);
        unsigned p1 = f2bfu(v4.z * fexp2(t4.z - l4.z))
                    | (f2bfu(v4.w * fexp2(t4.w - l4.w)) << 16);
        uint2 pp; pp.x = p0; pp.y = p1;
        *(uint2*)&w_s[i][u] = pp;                  // 8B store, 8B-aligned
    }
    __syncthreads();                               // b4

    // wave 0: fragments + 2 MFMAs + bf16 store (waves 1-3 retire)
    if (tid < 64) {
        const int half = tid >> 5;
        const int mm = tid & 31;
        short8v ka0, ka1, wf0, wf1;
        #pragma unroll
        for (int e = 0; e < 8; ++e) {
            ka0[e] = f2bf(k_s[8 * half + e][mm]);
            ka1[e] = f2bf(k_s[16 + 8 * half + e][mm]);
            wf0[e] = (short)w_s[8 * half + e][mm];
            wf1[e] = (short)w_s[16 + 8 * half + e][mm];
        }
        f32x16 acc;
        #pragma unroll
        for (int e = 0; e < 16; ++e) acc[e] = 0.f;
        acc = __builtin_amdgcn_mfma_f32_32x32x16_bf16(ka0, wf0, acc, 0, 0, 0);
        acc = __builtin_amdgcn_mfma_f32_32x32x16_bf16(ka1, wf1, acc, 0, 0, 0);

        ushort* kvout = ChKV + (long)blk * (D * D);
        #pragma unroll
        for (int reg = 0; reg < 16; ++reg) {
            const int d = (reg & 3) + 8 * (reg >> 2) + 4 * half;
            kvout[d * D + mm] = (ushort)f2bf(acc[reg]);
        }
    }
}

// ---------------- Kernel 2: inter-chunk scan (bf16 in/out, f32 state) --------
// In-place ChKV -> chunk-START states. 8-deep prefetch (verified structure).
__global__ __launch_bounds__(256)
void k2_scan(ushort* __restrict__ ChKV, const float* __restrict__ ChG)
{
    const int bh = blockIdx.x >> 2;
    const int dg = blockIdx.x & 3;
    const int tid = threadIdx.x;
    const int d = dg * 8 + (tid >> 5);
    const int m = tid & 31;

    const long kvoff = (long)bh * NC * (D * D) + d * D + m;
    const long goff = (long)bh * NC * D + m;

    ushort ka[8]; float ga[8];
    #pragma unroll
    for (int t = 0; t < 8; ++t) {
        ka[t] = ChKV[kvoff + (long)t * (D * D)];
        ga[t] = ChG[goff + (long)t * D];
    }
    float st = 0.f;
    for (int c0 = 0; c0 < NC; c0 += 8) {
        ushort kb[8]; float gb2[8];
        const bool more = (c0 + 8) < NC;
        #pragma unroll
        for (int t = 0; t < 8; ++t) {
            kb[t]  = more ? ChKV[kvoff + (long)(c0 + 8 + t) * (D * D)] : (ushort)0;
            gb2[t] = more ? ChG[goff + (long)(c0 + 8 + t) * D] : 0.f;
        }
        #pragma unroll
        for (int t = 0; t < 8; ++t) {
            ChKV[kvoff + (long)(c0 + t) * (D * D)] = (ushort)f2bf(st); // START state
            st = ga[t] * st + bf2f((short)ka[t]);
        }
        #pragma unroll
        for (int t = 0; t < 8; ++t) { ka[t] = kb[t]; ga[t] = gb2[t]; }
    }
}

// ---------------- Kernel 3: MFMA per-chunk outputs (r12/r14 verified body) ----
// One wave per chunk; 4 chunks per block. S0 read as bf16.
__global__ __launch_bounds__(256)
void k3_mfma(const float* __restrict__ Qp, const float* __restrict__ Kp,
             const float* __restrict__ Vp, const float* __restrict__ Gp,
             const ushort* __restrict__ S0b, float* __restrict__ Op)
{
    __shared__ __align__(16) float  l_s[4][L][36];
    __shared__ __align__(16) ushort w_s[4][L][40];
    __shared__ __align__(16) ushort a_s[4][L][40];
    __shared__ float tot[4][D];

    const int tid = threadIdx.x;
    const int wv = tid >> 6;
    const int lane = tid & 63;
    const int half = lane >> 5;
    const int m = lane & 31;

    const int chunk = blockIdx.x * 4 + wv;
    const int bh = chunk >> 7;
    const int c = chunk & (NC - 1);
    const int b = bh >> 4;
    const int h = bh & (H - 1);
    const long base = ((long)b * S + (long)c * L) * RS + h * D;
    const ushort* S0c = S0b + (long)chunk * (D * D);

    const float* qrow = Qp + base + (long)m * RS + 8 * half;
    const float* krow = Kp + base + (long)m * RS + 8 * half;
    float4 qv0 = *(const float4*)(qrow);
    float4 qv1 = *(const float4*)(qrow + 4);
    float4 qv2 = *(const float4*)(qrow + 16);
    float4 qv3 = *(const float4*)(qrow + 20);
    float4 kv0 = *(const float4*)(krow);
    float4 kv1 = *(const float4*)(krow + 4);
    float4 kv2 = *(const float4*)(krow + 16);
    float4 kv3 = *(const float4*)(krow + 20);
    short8v qa0, qa1, ka0, ka1;
    {
        float qf[16] = {qv0.x,qv0.y,qv0.z,qv0.w, qv1.x,qv1.y,qv1.z,qv1.w,
                        qv2.x,qv2.y,qv2.z,qv2.w, qv3.x,qv3.y,qv3.z,qv3.w};
        float kf[16] = {kv0.x,kv0.y,kv0.z,kv0.w, kv1.x,kv1.y,kv1.z,kv1.w,
                        kv2.x,kv2.y,kv2.z,kv2.w, kv3.x,kv3.y,kv3.z,kv3.w};
        #pragma unroll
        for (int e = 0; e < 8; ++e) {
            qa0[e] = f2bf(qf[e]);     qa1[e] = f2bf(qf[8 + e]);
            ka0[e] = f2bf(kf[e]);     ka1[e] = f2bf(kf[8 + e]);
        }
    }

    float cum[16];
    {
        const float* gcol = Gp + base + (long)(half * 16) * RS + m;
        float run = 0.f;
        #pragma unroll
        for (int t = 0; t < 16; ++t) {
            run += flog2(fmaxf(gcol[(long)t * RS], GEPS));
            cum[t] = run;
        }
    }
    if (half == 0) tot[wv][m] = cum[15];
    __syncthreads();                                 // b1
    {
        const float basel = (half == 1) ? tot[wv][m] : 0.f;
        #pragma unroll
        for (int t = 0; t < 16; ++t) cum[t] += basel;
    }
    const float e_a = cum[7], e_b = cum[15];

    {
        const float* vcol = Vp + base + (long)(half * 16) * RS + m;
        #pragma unroll
        for (int t = 0; t < 16; ++t) {
            const int r = half * 16 + t;
            const float e = (t < 8) ? e_a : e_b;
            const float w = vcol[(long)t * RS] * fexp2(e - cum[t]);
            w_s[wv][r][m] = (ushort)f2bf(w);
            l_s[wv][r][m] = cum[t];
        }
    }
    __syncthreads();                                 // b2

    f32x16 acc;
    #pragma unroll
    for (int e = 0; e < 16; ++e) acc[e] = 0.f;
    acc = __builtin_amdgcn_mfma_f32_32x32x16_bf16(qa0, ka0, acc, 0, 0, 0);
    acc = __builtin_amdgcn_mfma_f32_32x32x16_bf16(qa1, ka1, acc, 0, 0, 0);
    #pragma unroll
    for (int reg = 0; reg < 16; ++reg) {
        const int irow = (reg & 3) + 8 * (reg >> 2) + 4 * half;
        const float av = (m <= irow) ? acc[reg] : 0.f;
        a_s[wv][irow][m] = (ushort)f2bf(av);
    }
    __syncthreads();                                 // b3

    float li[16];
    #pragma unroll
    for (int reg = 0; reg < 16; ++reg)
        li[reg] = l_s[wv][(reg & 3) + 8 * (reg >> 2) + 4 * half][m];
    float es4[4];
    #pragma unroll
    for (int s = 0; s < 4; ++s) es4[s] = l_s[wv][8 * s + 7][m];

    // cross-chunk: 2^{l_i} * (Q . S0), S0 bf16 straight from global
    f32x16 sacc;
    #pragma unroll
    for (int e = 0; e < 16; ++e) sacc[e] = 0.f;
    {
        short8v sf0, sf1;
        #pragma unroll
        for (int e = 0; e < 8; ++e) {
            sf0[e] = (short)S0c[(8 * half + e) * D + m];
            sf1[e] = (short)S0c[(16 + 8 * half + e) * D + m];
        }
        sacc = __builtin_amdgcn_mfma_f32_32x32x16_bf16(qa0, sf0, sacc, 0, 0, 0);
        sacc = __builtin_amdgcn_mfma_f32_32x32x16_bf16(qa1, sf1, sacc, 0, 0, 0);
    }
    f32x16 out;
    #pragma unroll
    for (int reg = 0; reg < 16; ++reg) out[reg] = fexp2(li[reg]) * sacc[reg];

    #pragma unroll
    for (int ks = 0; ks < 2; ++ks) {
        const short8v af = *(const short8v*)&a_s[wv][m][16 * ks + 8 * half];
        short8v wf;
        #pragma unroll
        for (int e = 0; e < 8; ++e)
            wf[e] = (short)w_s[wv][16 * ks + 8 * half + e][m];
        #pragma unroll
        for (int par = 0; par < 2; ++par) {
            const int s = 2 * ks + par;
            short8v am;
            #pragma unroll
            for (int e = 0; e < 8; ++e) am[e] = (half == par) ? af[e] : (short)0;
            f32x16 p;
            #pragma unroll
            for (int e = 0; e < 16; ++e) p[e] = 0.f;
            p = __builtin_amdgcn_mfma_f32_32x32x16_bf16(am, wf, p, 0, 0, 0);
            #pragma unroll
            for (int reg = 0; reg < 16; ++reg)
                out[reg] += fexp2(fminf(li[reg] - es4[s], 120.f)) * p[reg];
        }
    }

    #pragma unroll
    for (int reg = 0; reg < 16; ++reg) {
        const int irow = (reg & 3) + 8 * (reg >> 2) + 4 * half;
        Op[base + (long)irow * RS + m] = out[reg];
    }
}

} // namespace

extern "C" void kernel_launch(void* const* d_in, const int* in_sizes, int n_in,
                              void* d_out, int out_size, void* d_ws, size_t ws_size,
                              hipStream_t stream)
{
    const float* q = (const float*)d_in[0];
    const float* k = (const float*)d_in[1];
    const float* v = (const float*)d_in[2];
    const float* g = (const float*)d_in[3];
    float* out = (float*)d_out;

    ushort* ChKV = (ushort*)d_ws;                          // [8192][32][32] bf16 (16.8 MB)
    float* ChG = (float*)(ChKV + (long)NBH * NC * D * D);  // [8192][32] f32    (1.05 MB)

    dim3 blk(256);
    k1_stage<<<dim3(NBH * NC), blk, 0, stream>>>(k, v, g, ChKV, ChG);
    k2_scan<<<dim3(NBH * 4), blk, 0, stream>>>(ChKV, ChG);
    k3_mfma<<<dim3(NBH * NC / 4), blk, 0, stream>>>(q, k, v, g, ChKV, out);
}

// Round 21
// 61.157 us; speedup vs baseline: 1.1132x; 1.0146x over previous
//
#include <hip/hip_runtime.h>

namespace {

constexpr int B = 4, S = 4096, H = 16, D = 32;
constexpr int L = 32;             // chunk length
constexpr int NC = S / L;         // 128 chunks per sequence
constexpr int NBH = B * H;        // 64
constexpr int RS = H * D;         // 512 floats between consecutive time steps
constexpr float GEPS = 1.52587890625e-05f;  // 2^-16 per-step decay clamp

// Lore (rounds 6-20, measured):
//  - launch_bounds(256,w) caps VGPR ~256/w; cap < live set => GB-scale spill.
//  - Scalar j-loops over LDS tiles are LDS-instruction bound -> MFMA.
//  - COLD scalar column loads are latency death (r13); OK L3-warm (r12).
//  - KVc MFMA needs TOTAL-scaled W; P MFMA needs SUB-scaled W (r15/r16).
//  - Fused consumers recomputing producer work pin at ~48us (r16-19);
//    pure consumers win. r21: k1 EXPORTS W_T(bf16)+l_T(f16) transposed so
//    k3 reads fragments as b128/b64 and does zero scan/W work.
//  - MFMA operand convention (HW-verified r12, absmax 0.5):
//    A-op: row = lane&31, k = 8*(lane>>5)+e (+16 for 2nd MFMA)
//    B-op: col = lane&31, same k
//    C/D : col = lane&31, row = (reg&3)+8*(reg>>2)+4*(lane>>5)

typedef __attribute__((ext_vector_type(8)))  short short8v;   // 8 bf16 = 4 VGPR
typedef __attribute__((ext_vector_type(16))) float f32x16;    // 16 f32 acc
typedef _Float16 half4v __attribute__((ext_vector_type(4)));  // 4 f16 = 8B

__device__ __forceinline__ float flog2(float x) { return __builtin_amdgcn_logf(x); }
__device__ __forceinline__ float fexp2(float x) { return __builtin_amdgcn_exp2f(x); }
__device__ __forceinline__ unsigned f2bfu(float f) {          // fp32 -> bf16 (RNE)
    unsigned u = __float_as_uint(f);
    return (u + 0x7FFFu + ((u >> 16) & 1u)) >> 16;
}
__device__ __forceinline__ short f2bf(float f) { return (short)f2bfu(f); }
__device__ __forceinline__ float bf2f(short s) {              // bf16 -> fp32
    return __uint_as_float(((unsigned)(ushort)s) << 16);
}

// ---------------- Kernel 1: scan + W/l export + chunk-KV MFMA -----------------
// One block per chunk (8192).
// lg -> final l (column scan).  w_s = v*2^{e_sub(i)-l_i} (SUB-scaled, for k3's P).
// Exports: W_T[chunk][m][r] bf16, L_T[chunk][m][r] f16 (transposed via LDS).
// ChKV[chunk][d][m] bf16 = sum_j K[j][d]*W_j[m]*2^{tot-e_sub(j)} (TOTAL-scaled).
// ChG[chunk][m] = 2^{tot[m]}.
__global__ __launch_bounds__(256)
void k1_stage(const float* __restrict__ Kp, const float* __restrict__ Vp,
              const float* __restrict__ Gp, ushort* __restrict__ ChKV,
              float* __restrict__ ChG, ushort* __restrict__ WT,
              _Float16* __restrict__ LT)
{
    __shared__ __align__(16) float  k_s[L][36];
    __shared__ __align__(16) float  lg[L][36];
    __shared__ __align__(16) ushort w_s[L][40];
    __shared__ float sub[8][D];
    __shared__ float totr[D];

    const int blk = blockIdx.x;                   // == chunk == bh*NC + c
    const int bh = blk >> 7;
    const int c = blk & (NC - 1);
    const int b = bh >> 4;
    const int h = bh & (H - 1);
    const long base = ((long)b * S + (long)c * L) * RS + h * D;

    const int tid = threadIdx.x;
    const int i = tid >> 3;          // row 0..31
    const int u = (tid & 7) * 4;     // col quad
    const long roff = base + (long)i * RS + u;

    float4 k4 = *(const float4*)(Kp + roff);
    float4 v4 = *(const float4*)(Vp + roff);
    float4 g4 = *(const float4*)(Gp + roff);
    *(float4*)&k_s[i][u] = k4;
    float4 lv;
    lv.x = flog2(fmaxf(g4.x, GEPS));
    lv.y = flog2(fmaxf(g4.y, GEPS));
    lv.z = flog2(fmaxf(g4.z, GEPS));
    lv.w = flog2(fmaxf(g4.w, GEPS));
    *(float4*)&lg[i][u] = lv;
    __syncthreads();                               // b1

    // column scan: thread -> (column m, 4-row group t)
    const int m = tid & 31, t = tid >> 5;
    const int r0 = t * 4;
    float c0 = lg[r0 + 0][m];
    float c1 = c0 + lg[r0 + 1][m];
    float c2 = c1 + lg[r0 + 2][m];
    float c3 = c2 + lg[r0 + 3][m];
    sub[t][m] = c3;
    __syncthreads();                               // b2

    {
        float sb[8];
        float total = 0.f;
        #pragma unroll
        for (int tt = 0; tt < 8; ++tt) { sb[tt] = sub[tt][m]; total += sb[tt]; }
        float base_l = 0.f;
        #pragma unroll
        for (int tt = 0; tt < 8; ++tt) { if (tt < t) base_l += sb[tt]; }
        lg[r0 + 0][m] = base_l + c0;
        lg[r0 + 1][m] = base_l + c1;
        lg[r0 + 2][m] = base_l + c2;
        lg[r0 + 3][m] = base_l + c3;
        if (t == 0) totr[m] = total;
        if (t == 1) ChG[(long)blk * D + m] = fexp2(total);
    }
    __syncthreads();                               // b3 (lg final)

    // W SUB-scaled, elementwise in row layout (v4 in regs; e_sub = lg[i|7])
    {
        float4 l4 = *(float4*)&lg[i][u];
        float4 e4 = *(float4*)&lg[i | 7][u];
        unsigned p0 = f2bfu(v4.x * fexp2(e4.x - l4.x))
                    | (f2bfu(v4.y * fexp2(e4.y - l4.y)) << 16);
        unsigned p1 = f2bfu(v4.z * fexp2(e4.z - l4.z))
                    | (f2bfu(v4.w * fexp2(e4.w - l4.w)) << 16);
        uint2 pp; pp.x = p0; pp.y = p1;
        *(uint2*)&w_s[i][u] = pp;
    }
    __syncthreads();                               // b4 (w_s ready)

    // ---- transposed exports: thread -> (mcol = tid>>3, rq = (tid&7)*4) ----
    {
        const int mcol = tid >> 3;
        const int rq = (tid & 7) * 4;
        ushort wq[4];
        half4v lq;
        #pragma unroll
        for (int z = 0; z < 4; ++z) {
            wq[z] = w_s[rq + z][mcol];
            lq[z] = (_Float16)lg[rq + z][mcol];
        }
        uint2 wp;
        wp.x = (unsigned)wq[0] | ((unsigned)wq[1] << 16);
        wp.y = (unsigned)wq[2] | ((unsigned)wq[3] << 16);
        *(uint2*)(WT + (long)blk * 1024 + mcol * 32 + rq) = wp;
        *(half4v*)(LT + (long)blk * 1024 + mcol * 32 + rq) = lq;
    }

    // ---- wave 0: TOTAL-rescaled fragments + 2 MFMAs + bf16 ChKV store ----
    if (tid < 64) {
        const int half = tid >> 5;
        const int mm = tid & 31;
        const float es0_ = lg[7][mm],  es1_ = lg[15][mm];
        const float es2_ = lg[23][mm], es3_ = lg[31][mm];   // es3_ == total
        const float fac0 = fexp2(es3_ - (half ? es1_ : es0_));  // rows 8h+e
        const float fac1 = fexp2(es3_ - (half ? es3_ : es2_));  // rows 16+8h+e
        short8v ka0, ka1, wf0, wf1;
        #pragma unroll
        for (int e = 0; e < 8; ++e) {
            ka0[e] = f2bf(k_s[8 * half + e][mm]);
            ka1[e] = f2bf(k_s[16 + 8 * half + e][mm]);
            wf0[e] = f2bf(bf2f((short)w_s[8 * half + e][mm]) * fac0);
            wf1[e] = f2bf(bf2f((short)w_s[16 + 8 * half + e][mm]) * fac1);
        }
        f32x16 acc;
        #pragma unroll
        for (int e = 0; e < 16; ++e) acc[e] = 0.f;
        acc = __builtin_amdgcn_mfma_f32_32x32x16_bf16(ka0, wf0, acc, 0, 0, 0);
        acc = __builtin_amdgcn_mfma_f32_32x32x16_bf16(ka1, wf1, acc, 0, 0, 0);

        ushort* kvout = ChKV + (long)blk * (D * D);
        #pragma unroll
        for (int reg = 0; reg < 16; ++reg) {
            const int d = (reg & 3) + 8 * (reg >> 2) + 4 * half;
            kvout[d * D + mm] = (ushort)f2bf(acc[reg]);
        }
    }
}

// ---------------- Kernel 2: inter-chunk scan (bf16 in/out, f32 state) --------
__global__ __launch_bounds__(256)
void k2_scan(ushort* __restrict__ ChKV, const float* __restrict__ ChG)
{
    const int bh = blockIdx.x >> 2;
    const int dg = blockIdx.x & 3;
    const int tid = threadIdx.x;
    const int d = dg * 8 + (tid >> 5);
    const int m = tid & 31;

    const long kvoff = (long)bh * NC * (D * D) + d * D + m;
    const long goff = (long)bh * NC * D + m;

    ushort ka[8]; float ga[8];
    #pragma unroll
    for (int t = 0; t < 8; ++t) {
        ka[t] = ChKV[kvoff + (long)t * (D * D)];
        ga[t] = ChG[goff + (long)t * D];
    }
    float st = 0.f;
    for (int c0 = 0; c0 < NC; c0 += 8) {
        ushort kb[8]; float gb2[8];
        const bool more = (c0 + 8) < NC;
        #pragma unroll
        for (int t = 0; t < 8; ++t) {
            kb[t]  = more ? ChKV[kvoff + (long)(c0 + 8 + t) * (D * D)] : (ushort)0;
            gb2[t] = more ? ChG[goff + (long)(c0 + 8 + t) * D] : 0.f;
        }
        #pragma unroll
        for (int t = 0; t < 8; ++t) {
            ChKV[kvoff + (long)(c0 + t) * (D * D)] = (ushort)f2bf(st); // START
            st = ga[t] * st + bf2f((short)ka[t]);
        }
        #pragma unroll
        for (int t = 0; t < 8; ++t) { ka[t] = kb[t]; ga[t] = gb2[t]; }
    }
}

// ---------------- Kernel 3: pure-consumer MFMA outputs ------------------------
// One wave per chunk; 4 chunks per block; ONE barrier.
// Reads Q,K (b128), W_T (2 b128), L_T (4 b64), S0 (16 scalar bf16).
__global__ __launch_bounds__(256)
void k3_mfma(const float* __restrict__ Qp, const float* __restrict__ Kp,
             const ushort* __restrict__ WT, const _Float16* __restrict__ LT,
             const ushort* __restrict__ S0b, float* __restrict__ Op)
{
    __shared__ __align__(16) ushort a_s[4][L][40];   // masked Gram, bf16

    const int tid = threadIdx.x;
    const int wv = tid >> 6;
    const int lane = tid & 63;
    const int half = lane >> 5;
    const int m = lane & 31;

    const int chunk = blockIdx.x * 4 + wv;
    const int bh = chunk >> 7;
    const int c = chunk & (NC - 1);
    const int b = bh >> 4;
    const int h = bh & (H - 1);
    const long base = ((long)b * S + (long)c * L) * RS + h * D;
    const ushort* S0c = S0b + (long)chunk * (D * D);

    // Q/K fragments (row-major b128, r12-verified pattern)
    const float* qrow = Qp + base + (long)m * RS + 8 * half;
    const float* krow = Kp + base + (long)m * RS + 8 * half;
    float4 qv0 = *(const float4*)(qrow);
    float4 qv1 = *(const float4*)(qrow + 4);
    float4 qv2 = *(const float4*)(qrow + 16);
    float4 qv3 = *(const float4*)(qrow + 20);
    float4 kv0 = *(const float4*)(krow);
    float4 kv1 = *(const float4*)(krow + 4);
    float4 kv2 = *(const float4*)(krow + 16);
    float4 kv3 = *(const float4*)(krow + 20);
    short8v qa0, qa1, ka0, ka1;
    {
        float qf[16] = {qv0.x,qv0.y,qv0.z,qv0.w, qv1.x,qv1.y,qv1.z,qv1.w,
                        qv2.x,qv2.y,qv2.z,qv2.w, qv3.x,qv3.y,qv3.z,qv3.w};
        float kf[16] = {kv0.x,kv0.y,kv0.z,kv0.w, kv1.x,kv1.y,kv1.z,kv1.w,
                        kv2.x,kv2.y,kv2.z,kv2.w, kv3.x,kv3.y,kv3.z,kv3.w};
        #pragma unroll
        for (int e = 0; e < 8; ++e) {
            qa0[e] = f2bf(qf[e]);     qa1[e] = f2bf(qf[8 + e]);
            ka0[e] = f2bf(kf[e]);     ka1[e] = f2bf(kf[8 + e]);
        }
    }

    // W fragments: 2 b128 from W_T[chunk][m][.]
    const ushort* Wc = WT + (long)chunk * 1024 + m * 32;
    const short8v wf0 = *(const short8v*)(Wc + 8 * half);
    const short8v wf1 = *(const short8v*)(Wc + 16 + 8 * half);

    // l at this lane's C-rows: 4 b64 from L_T; es4 via shfl
    const _Float16* Lc = LT + (long)chunk * 1024 + m * 32;
    float li[16];
    #pragma unroll
    for (int j = 0; j < 4; ++j) {
        half4v lq = *(const half4v*)(Lc + 8 * j + 4 * half);
        li[4 * j + 0] = (float)lq[0];
        li[4 * j + 1] = (float)lq[1];
        li[4 * j + 2] = (float)lq[2];
        li[4 * j + 3] = (float)lq[3];
    }
    float es4[4];
    #pragma unroll
    for (int s = 0; s < 4; ++s) {
        const float tmp = __shfl_xor(li[4 * s + 3], 32);
        es4[s] = half ? li[4 * s + 3] : tmp;     // l at row 8s+7
    }

    // Gram A = Q.K^T -> masked bf16 a_s
    {
        f32x16 acc;
        #pragma unroll
        for (int e = 0; e < 16; ++e) acc[e] = 0.f;
        acc = __builtin_amdgcn_mfma_f32_32x32x16_bf16(qa0, ka0, acc, 0, 0, 0);
        acc = __builtin_amdgcn_mfma_f32_32x32x16_bf16(qa1, ka1, acc, 0, 0, 0);
        #pragma unroll
        for (int reg = 0; reg < 16; ++reg) {
            const int irow = (reg & 3) + 8 * (reg >> 2) + 4 * half;
            const float av = (m <= irow) ? acc[reg] : 0.f;
            a_s[wv][irow][m] = (ushort)f2bf(av);
        }
    }

    // cross-chunk: 2^{l_i} * (Q . S0), S0 bf16 from global (L3)
    f32x16 sacc;
    #pragma unroll
    for (int e = 0; e < 16; ++e) sacc[e] = 0.f;
    {
        short8v sf0, sf1;
        #pragma unroll
        for (int e = 0; e < 8; ++e) {
            sf0[e] = (short)S0c[(8 * half + e) * D + m];
            sf1[e] = (short)S0c[(16 + 8 * half + e) * D + m];
        }
        sacc = __builtin_amdgcn_mfma_f32_32x32x16_bf16(qa0, sf0, sacc, 0, 0, 0);
        sacc = __builtin_amdgcn_mfma_f32_32x32x16_bf16(qa1, sf1, sacc, 0, 0, 0);
    }
    f32x16 out;
    #pragma unroll
    for (int reg = 0; reg < 16; ++reg) out[reg] = fexp2(li[reg]) * sacc[reg];

    __syncthreads();                                 // ONLY barrier: a_s ready

    #pragma unroll
    for (int ks = 0; ks < 2; ++ks) {
        const short8v af = *(const short8v*)&a_s[wv][m][16 * ks + 8 * half];
        const short8v wf = ks ? wf1 : wf0;
        #pragma unroll
        for (int par = 0; par < 2; ++par) {
            const int s = 2 * ks + par;
            short8v am;
            #pragma unroll
            for (int e = 0; e < 8; ++e) am[e] = (half == par) ? af[e] : (short)0;
            f32x16 p;
            #pragma unroll
            for (int e = 0; e < 16; ++e) p[e] = 0.f;
            p = __builtin_amdgcn_mfma_f32_32x32x16_bf16(am, wf, p, 0, 0, 0);
            #pragma unroll
            for (int reg = 0; reg < 16; ++reg)
                out[reg] += fexp2(fminf(li[reg] - es4[s], 120.f)) * p[reg];
        }
    }

    #pragma unroll
    for (int reg = 0; reg < 16; ++reg) {
        const int irow = (reg & 3) + 8 * (reg >> 2) + 4 * half;
        Op[base + (long)irow * RS + m] = out[reg];
    }
}

} // namespace

extern "C" void kernel_launch(void* const* d_in, const int* in_sizes, int n_in,
                              void* d_out, int out_size, void* d_ws, size_t ws_size,
                              hipStream_t stream)
{
    const float* q = (const float*)d_in[0];
    const float* k = (const float*)d_in[1];
    const float* v = (const float*)d_in[2];
    const float* g = (const float*)d_in[3];
    float* out = (float*)d_out;

    ushort* ChKV = (ushort*)d_ws;                           // [8192][1024] bf16 (16.8 MB)
    float* ChG = (float*)(ChKV + (long)NBH * NC * D * D);   // [8192][32] f32   (1.05 MB)
    ushort* WT = (ushort*)(ChG + (long)NBH * NC * D);       // [8192][1024] bf16 (16.8 MB)
    _Float16* LT = (_Float16*)(WT + (long)NBH * NC * D * D);// [8192][1024] f16  (16.8 MB)

    dim3 blk(256);
    k1_stage<<<dim3(NBH * NC), blk, 0, stream>>>(k, v, g, ChKV, ChG, WT, LT);
    k2_scan<<<dim3(NBH * 4), blk, 0, stream>>>(ChKV, ChG);
    k3_mfma<<<dim3(NBH * NC / 4), blk, 0, stream>>>(q, k, WT, LT, ChKV, out);
}